// Round 8
// baseline (301.884 us; speedup 1.0000x reference)
//
#include <hip/hip_runtime.h>
#include <hip/hip_bf16.h>

#define DIMV 64
#define CH 64
#define EPSB 1e-3f

using bf16x8 = __attribute__((ext_vector_type(8))) short;
using f32x16 = __attribute__((ext_vector_type(16))) float;

__device__ __forceinline__ unsigned short f2bf(float f) {
    union { float f; unsigned u; } x; x.f = f;
    unsigned r = x.u + 0x7fff + ((x.u >> 16) & 1);   // round-to-nearest-even
    return (unsigned short)(r >> 16);
}
__device__ __forceinline__ float bf2f(unsigned short u) {
    union { unsigned u; float f; } x; x.u = ((unsigned)u) << 16;
    return x.f;
}

__global__ void scatter_kernel(const float* __restrict__ x, const int* __restrict__ idx,
                               float* __restrict__ grid, int n_total) {
    int tid = blockIdx.x * blockDim.x + threadIdx.x;
    if (tid >= n_total) return;
    int n = tid >> 6, c = tid & 63;
    int ix = idx[n * 3 + 0], iy = idx[n * 3 + 1], iz = idx[n * 3 + 2];
    atomicAdd(&grid[(size_t)(((ix * DIMV) + iy) * DIMV + iz) * CH + c], x[tid]);
}

// ---------------- weight repack into MFMA B-fragment layout ----------------
__global__ void wprep_kernel(const float* __restrict__ K, unsigned short* __restrict__ wbuf) {
    int t = blockIdx.x * 256 + threadIdx.x;
    if (t >= 27 * 4 * 2 * 64 * 8) return;
    int j = t & 7;
    int l = (t >> 3) & 63;
    int nt = (t >> 9) & 1;
    int kkl = (t >> 10) & 3;
    int d = t >> 12;
    int ci = kkl * 16 + (l >> 5) * 8 + j;
    int co = nt * 32 + (l & 31);
    wbuf[t] = f2bf(K[((size_t)d * 64 + ci) * 64 + co]);
}

__global__ void wprep_mlp(const float* __restrict__ W, unsigned short* __restrict__ wm) {
    int t = blockIdx.x * 256 + threadIdx.x;
    if (t >= 4 * 2 * 64 * 8) return;
    int j = t & 7;
    int l = (t >> 3) & 63;
    int nt = (t >> 9) & 1;
    int kkl = (t >> 10) & 3;
    int ci = kkl * 16 + (l >> 5) * 8 + j;
    int co = nt * 32 + (l & 31);
    wm[t] = f2bf(W[(size_t)ci * 64 + co]);
}

// ---------------- MFMA conv v6: 4 waves, wave = 4 y-cols, A/B-reuse-max ----------------
// Block: output 4x4 xy x 32 z. Wave w = x-col w, covering 4 y-cols x 32 z x 64 co.
// Per (dx,dz,kkl): 6 A ds_reads (y-sources 0..5) + 6 B loads (3dy x 2nt) -> 24 MFMAs.
// B tensor loaded exactly ONCE per wave (216 loads). A-slab 153 KB, 1 block/CU.
// FUSE=1: stage reads fp32 scatter grid * inv (pack fused). FUSE=0: bf16 grid.
template <int FUSE>
__global__ __launch_bounds__(256) void conv_mfma(
    const unsigned short* __restrict__ Gb, const float* __restrict__ Gf,
    const float* __restrict__ inv, const unsigned short* __restrict__ wbuf,
    const float* __restrict__ cb, const float* __restrict__ g,
    const float* __restrict__ be, const float* __restrict__ m,
    const float* __restrict__ v, unsigned short* __restrict__ out) {
    __shared__ __align__(16) unsigned short slab[612 * 128];   // 156672 B
    const int tid = threadIdx.x;
    const int lane = tid & 63;
    const int w = tid >> 6;          // wave 0..3 = output x-col
    const int lz = lane & 31;
    const int kg = lane >> 5;
    const int BX = blockIdx.x, BY = blockIdx.y, BZ = blockIdx.z;
    const int x0 = 4 * BX - 1, y0 = 4 * BY - 1;
    const int zbase = 32 * BZ - 1;   // odd

    // Stage A slab: 9792 chunks of 16B (8ch). Pre-swizzled global source,
    // linear LDS write. Slot s at row (col,zp) holds ch-pair chunk cp = s^(zp&15).
    for (int it = 0; it < 39; ++it) {
        int idx = it * 256 + tid;
        if (idx < 9792) {
            int s = idx & 15;
            int r = idx >> 4;               // 0..611
            int zp = r % 17;
            int ryx = r / 17;               // 0..35
            int xx = x0 + ryx / 6;
            int yy = y0 + ryx % 6;
            int cp = s ^ (zp & 15);
            int c = cp >> 1, p = cp & 1;
            int zz = zbase + 2 * zp + p;
            if (FUSE) {
                __align__(16) unsigned short tmp[8] = {0, 0, 0, 0, 0, 0, 0, 0};
                if ((unsigned)xx < DIMV && (unsigned)yy < DIMV && (unsigned)zz < DIMV) {
                    int vox = ((xx * DIMV) + yy) * DIMV + zz;
                    const float* src = Gf + (size_t)vox * CH + c * 8;
                    float sc = inv[vox];
#pragma unroll
                    for (int j = 0; j < 8; ++j) tmp[j] = f2bf(src[j] * sc);
                }
                *(int4*)(slab + (size_t)idx * 8) = *(const int4*)tmp;
            } else {
                int4 val = make_int4(0, 0, 0, 0);
                if ((unsigned)xx < DIMV && (unsigned)yy < DIMV && (unsigned)zz < DIMV)
                    val = *(const int4*)(Gb + (size_t)(((xx * DIMV) + yy) * DIMV + zz) * CH + c * 8);
                *(int4*)(slab + (size_t)idx * 8) = val;
            }
        }
    }
    __syncthreads();

    f32x16 acc[4][2];
#pragma unroll
    for (int yc = 0; yc < 4; ++yc)
#pragma unroll
        for (int nt = 0; nt < 2; ++nt)
#pragma unroll
            for (int r = 0; r < 16; ++r) acc[yc][nt][r] = 0.f;

#pragma unroll
    for (int dx = 0; dx < 3; ++dx)
#pragma unroll
        for (int dz = 0; dz < 3; ++dz) {
            const int zval = lz + dz;              // 0..33
            const int zp = zval >> 1, p = zval & 1;
            const int rb = ((w + dx) * 6) * 17 + zp;
#pragma unroll
            for (int kkl = 0; kkl < 4; ++kkl) {
                const int slot = ((kkl * 2 + kg) * 2 + p) ^ (zp & 15);
                bf16x8 a[6];
#pragma unroll
                for (int ys = 0; ys < 6; ++ys)
                    a[ys] = *(const bf16x8*)(slab + (rb + ys * 17) * 128 + slot * 8);
                bf16x8 bb[3][2];
#pragma unroll
                for (int dy = 0; dy < 3; ++dy) {
                    const unsigned short* wd =
                        wbuf + (size_t)(dx * 9 + dy * 3 + dz) * 4096 + (kkl * 2) * 512 + lane * 8;
                    bb[dy][0] = *(const bf16x8*)(wd);
                    bb[dy][1] = *(const bf16x8*)(wd + 512);
                }
#pragma unroll
                for (int dy = 0; dy < 3; ++dy)
#pragma unroll
                    for (int yc = 0; yc < 4; ++yc) {
                        acc[yc][0] = __builtin_amdgcn_mfma_f32_32x32x16_bf16(
                            a[yc + dy], bb[dy][0], acc[yc][0], 0, 0, 0);
                        acc[yc][1] = __builtin_amdgcn_mfma_f32_32x32x16_bf16(
                            a[yc + dy], bb[dy][1], acc[yc][1], 0, 0, 0);
                    }
            }
        }

    const int x_out = 4 * BX + w;
#pragma unroll
    for (int yc = 0; yc < 4; ++yc) {
        int y_out = 4 * BY + yc;
#pragma unroll
        for (int nt = 0; nt < 2; ++nt) {
            int co = nt * 32 + lz;
            float scale = g[co] * rsqrtf(v[co] + EPSB);
            float shift = be[co] - m[co] * scale;
            float bias = cb[co];
            size_t base = (size_t)((x_out * DIMV) + y_out) * DIMV * CH + co;
#pragma unroll
            for (int r = 0; r < 16; ++r) {
                int zrow = (r & 3) + 8 * (r >> 2) + 4 * kg;
                int z = BZ * 32 + zrow;
                float val = fmaxf(acc[yc][nt][r] + bias, 0.f) * scale + shift;
                out[base + (size_t)z * CH] = f2bf(val);
            }
        }
    }
}

// ---------------- fused point-MLP (MFMA) + trilinear gather + final write ----------------
__global__ __launch_bounds__(256) void mlp_gather(
    const float* __restrict__ x, const unsigned short* __restrict__ wfrag,
    const float* __restrict__ b, const float* __restrict__ g,
    const float* __restrict__ be, const float* __restrict__ m,
    const float* __restrict__ v, const unsigned short* __restrict__ grid,
    const float* __restrict__ pts, float* __restrict__ out, int npts) {
    __shared__ float lds[128 * 64];          // 32 KB
    const int w = threadIdx.x >> 6;
    const int lane = threadIdx.x & 63;
    const int col = lane & 31;
    const int kg = lane >> 5;
    const int p0 = (blockIdx.x * 4 + w) * 32;

    if (p0 < npts) {
        bf16x8 a[4];
        const float* xr = x + (size_t)(p0 + col) * CH + kg * 8;
#pragma unroll
        for (int kk = 0; kk < 4; ++kk) {
            const float* p = xr + kk * 16;
            bf16x8 t;
#pragma unroll
            for (int j = 0; j < 8; ++j) t[j] = (short)f2bf(p[j]);
            a[kk] = t;
        }
        f32x16 acc[2];
#pragma unroll
        for (int nt = 0; nt < 2; ++nt)
#pragma unroll
            for (int r = 0; r < 16; ++r) acc[nt][r] = 0.f;
#pragma unroll
        for (int kk = 0; kk < 4; ++kk) {
            bf16x8 b0 = *(const bf16x8*)(wfrag + (kk * 2 + 0) * 512 + lane * 8);
            bf16x8 b1 = *(const bf16x8*)(wfrag + (kk * 2 + 1) * 512 + lane * 8);
            acc[0] = __builtin_amdgcn_mfma_f32_32x32x16_bf16(a[kk], b0, acc[0], 0, 0, 0);
            acc[1] = __builtin_amdgcn_mfma_f32_32x32x16_bf16(a[kk], b1, acc[1], 0, 0, 0);
        }
#pragma unroll
        for (int nt = 0; nt < 2; ++nt) {
            int co = nt * 32 + col;
            float scale = g[co] * rsqrtf(v[co] + EPSB);
            float shift = be[co] - m[co] * scale;
            float bias = b[co];
#pragma unroll
            for (int r = 0; r < 16; ++r) {
                int row = (r & 3) + 8 * (r >> 2) + 4 * kg;
                float val = fmaxf(acc[nt][r] + bias, 0.f) * scale + shift;
                lds[(w * 32 + row) * 64 + co] = val;
            }
        }
    }
    __syncthreads();

    const int pblk = blockIdx.x * 128;
#pragma unroll 4
    for (int i = 0; i < 32; ++i) {
        int idx = i * 256 + threadIdx.x;
        int pl = idx >> 6;
        int c = idx & 63;
        int pt = pblk + pl;
        if (pt >= npts) break;
        float px = fminf(fmaxf(pts[pt * 3 + 0], 0.f), (float)(DIMV - 1));
        float py = fminf(fmaxf(pts[pt * 3 + 1], 0.f), (float)(DIMV - 1));
        float pz = fminf(fmaxf(pts[pt * 3 + 2], 0.f), (float)(DIMV - 1));
        float fx = floorf(px), fy = floorf(py), fz = floorf(pz);
        float tx = px - fx, ty = py - fy, tz = pz - fz;
        int x0 = (int)fx, y0 = (int)fy, z0 = (int)fz;
        int x1 = min(x0 + 1, DIMV - 1), y1 = min(y0 + 1, DIMV - 1), z1 = min(z0 + 1, DIMV - 1);
        float wx0 = 1.f - tx, wy0 = 1.f - ty, wz0 = 1.f - tz;
        float acc = lds[pl * 64 + c];
        acc = fmaf(wx0 * wy0 * wz0, bf2f(grid[(size_t)(((x0 * DIMV) + y0) * DIMV + z0) * CH + c]), acc);
        acc = fmaf(wx0 * wy0 * tz,  bf2f(grid[(size_t)(((x0 * DIMV) + y0) * DIMV + z1) * CH + c]), acc);
        acc = fmaf(wx0 * ty * wz0,  bf2f(grid[(size_t)(((x0 * DIMV) + y1) * DIMV + z0) * CH + c]), acc);
        acc = fmaf(wx0 * ty * tz,   bf2f(grid[(size_t)(((x0 * DIMV) + y1) * DIMV + z1) * CH + c]), acc);
        acc = fmaf(tx * wy0 * wz0,  bf2f(grid[(size_t)(((x1 * DIMV) + y0) * DIMV + z0) * CH + c]), acc);
        acc = fmaf(tx * wy0 * tz,   bf2f(grid[(size_t)(((x1 * DIMV) + y0) * DIMV + z1) * CH + c]), acc);
        acc = fmaf(tx * ty * wz0,   bf2f(grid[(size_t)(((x1 * DIMV) + y1) * DIMV + z0) * CH + c]), acc);
        acc = fmaf(tx * ty * tz,    bf2f(grid[(size_t)(((x1 * DIMV) + y1) * DIMV + z1) * CH + c]), acc);
        out[(size_t)pt * CH + c] = acc;
    }
}

extern "C" void kernel_launch(void* const* d_in, const int* in_sizes, int n_in,
                              void* d_out, int out_size, void* d_ws, size_t ws_size,
                              hipStream_t stream) {
    const float* inputs = (const float*)d_in[0];
    const float* pt_coords = (const float*)d_in[1];
    const int* voxel_indexes = (const int*)d_in[2];
    const float* ppvi = (const float*)d_in[3];
    const float* w_mlp = (const float*)d_in[4];
    const float* b_mlp = (const float*)d_in[5];
    const float* g0 = (const float*)d_in[6];
    const float* be0 = (const float*)d_in[7];
    const float* m0 = (const float*)d_in[8];
    const float* v0 = (const float*)d_in[9];
    const float* k1 = (const float*)d_in[10];
    const float* cb1 = (const float*)d_in[11];
    const float* g1 = (const float*)d_in[12];
    const float* be1 = (const float*)d_in[13];
    const float* m1 = (const float*)d_in[14];
    const float* v1 = (const float*)d_in[15];
    const float* k2 = (const float*)d_in[16];
    const float* cb2 = (const float*)d_in[17];
    const float* g2 = (const float*)d_in[18];
    const float* be2 = (const float*)d_in[19];
    const float* m2 = (const float*)d_in[20];
    const float* v2 = (const float*)d_in[21];
    float* out = (float*)d_out;

    char* ws = (char*)d_ws;
    // [0, 67.1M):     A fp32 scatter grid; after conv1 done, G3 bf16 reuses [0,33.5M)
    // [67.1M,100.7M): G2 bf16 (conv1 output, conv2 input)
    // [100.7M, +):    wbuf1, wbuf2 (221184 B each), wmlp (8192 B)
    float* A = (float*)ws;
    unsigned short* G3 = (unsigned short*)ws;
    unsigned short* G2 = (unsigned short*)(ws + 67108864);
    unsigned short* wbuf1 = (unsigned short*)(ws + 100663296);
    unsigned short* wbuf2 = (unsigned short*)(ws + 100884480);
    unsigned short* wmlp = (unsigned short*)(ws + 101105664);

    const int n_total = in_sizes[0];           // N * C
    const int npts = n_total / CH;
    const int nblk = (n_total + 255) / 256;
    const size_t grid_elems = (size_t)DIMV * DIMV * DIMV * CH;

    hipMemsetAsync(A, 0, grid_elems * sizeof(float), stream);
    wprep_mlp<<<16, 256, 0, stream>>>(w_mlp, wmlp);
    wprep_kernel<<<432, 256, 0, stream>>>(k1, wbuf1);
    wprep_kernel<<<432, 256, 0, stream>>>(k2, wbuf2);
    scatter_kernel<<<nblk, 256, 0, stream>>>(inputs, voxel_indexes, A, n_total);

    dim3 cgrid(16, 16, 2);
    conv_mfma<1><<<cgrid, 256, 0, stream>>>(nullptr, A, ppvi, wbuf1, cb1, g1, be1, m1, v1, G2);
    conv_mfma<0><<<cgrid, 256, 0, stream>>>(G2, nullptr, nullptr, wbuf2, cb2, g2, be2, m2, v2, G3);

    mlp_gather<<<(npts + 127) / 128, 256, 0, stream>>>(
        inputs, wmlp, b_mlp, g0, be0, m0, v0, G3, pt_coords, out, npts);
}

// Round 9
// 286.547 us; speedup vs baseline: 1.0535x; 1.0535x over previous
//
#include <hip/hip_runtime.h>
#include <hip/hip_bf16.h>

#define DIMV 64
#define CH 64
#define EPSB 1e-3f

using bf16x8 = __attribute__((ext_vector_type(8))) short;
using f32x16 = __attribute__((ext_vector_type(16))) float;

__device__ __forceinline__ unsigned short f2bf(float f) {
    union { float f; unsigned u; } x; x.f = f;
    unsigned r = x.u + 0x7fff + ((x.u >> 16) & 1);   // round-to-nearest-even
    return (unsigned short)(r >> 16);
}
__device__ __forceinline__ float bf2f(unsigned short u) {
    union { unsigned u; float f; } x; x.u = ((unsigned)u) << 16;
    return x.f;
}

__global__ void scatter_kernel(const float* __restrict__ x, const int* __restrict__ idx,
                               float* __restrict__ grid, int n_total) {
    int tid = blockIdx.x * blockDim.x + threadIdx.x;
    if (tid >= n_total) return;
    int n = tid >> 6, c = tid & 63;
    int ix = idx[n * 3 + 0], iy = idx[n * 3 + 1], iz = idx[n * 3 + 2];
    atomicAdd(&grid[(size_t)(((ix * DIMV) + iy) * DIMV + iz) * CH + c], x[tid]);
}

// ---------------- weight repack into MFMA B-fragment layout ----------------
__global__ void wprep_kernel(const float* __restrict__ K, unsigned short* __restrict__ wbuf) {
    int t = blockIdx.x * 256 + threadIdx.x;
    if (t >= 27 * 4 * 2 * 64 * 8) return;
    int j = t & 7;
    int l = (t >> 3) & 63;
    int nt = (t >> 9) & 1;
    int kkl = (t >> 10) & 3;
    int d = t >> 12;
    int ci = kkl * 16 + (l >> 5) * 8 + j;
    int co = nt * 32 + (l & 31);
    wbuf[t] = f2bf(K[((size_t)d * 64 + ci) * 64 + co]);
}

__global__ void wprep_mlp(const float* __restrict__ W, unsigned short* __restrict__ wm) {
    int t = blockIdx.x * 256 + threadIdx.x;
    if (t >= 4 * 2 * 64 * 8) return;
    int j = t & 7;
    int l = (t >> 3) & 63;
    int nt = (t >> 9) & 1;
    int kkl = (t >> 10) & 3;
    int ci = kkl * 16 + (l >> 5) * 8 + j;
    int co = nt * 32 + (l & 31);
    wm[t] = f2bf(W[(size_t)ci * 64 + co]);
}

// ---------------- MFMA conv v7: r6 structure + per-wave d-stagger ----------------
// C-tile 4x4 xy x 32 z, 8 waves, wave = 2 y-adjacent columns. A-slab 153 KB.
// Wave w walks d in rotated order (3w + s) mod 27 (commutative accumulation,
// slab read-only) -> waves sit at different load/MFMA phases at any instant.
// Depth-1 B ping-pong in registers. FUSE=1: stage reads fp32 grid * inv.
template <int FUSE>
__global__ __launch_bounds__(512) void conv_mfma(
    const unsigned short* __restrict__ Gb, const float* __restrict__ Gf,
    const float* __restrict__ inv, const unsigned short* __restrict__ wbuf,
    const float* __restrict__ cb, const float* __restrict__ g,
    const float* __restrict__ be, const float* __restrict__ m,
    const float* __restrict__ v, unsigned short* __restrict__ out) {
    __shared__ __align__(16) unsigned short slab[612 * 128];   // 156672 B
    const int tid = threadIdx.x;
    const int lane = tid & 63;
    const int w = tid >> 6;          // wave 0..7
    const int cx = w >> 1;           // x-col 0..3
    const int cy0 = 2 * (w & 1);     // y-col base 0 or 2
    const int lz = lane & 31;
    const int kg = lane >> 5;
    const int BX = blockIdx.x, BY = blockIdx.y, BZ = blockIdx.z;
    const int x0 = 4 * BX - 1, y0 = 4 * BY - 1;
    const int zbase = 32 * BZ - 1;   // odd

    // Stage A slab: 9792 chunks of 16B. Pre-swizzled global source, linear LDS
    // write. Slot s at row (col,zp) holds ch-pair chunk cp = s ^ (zp&15).
    for (int it = 0; it < 20; ++it) {
        int idx = it * 512 + tid;
        if (idx < 9792) {
            int s = idx & 15;
            int r = idx >> 4;               // 0..611
            int zp = r % 17;
            int ryx = r / 17;               // 0..35
            int xx = x0 + ryx / 6;
            int yy = y0 + ryx % 6;
            int cp = s ^ (zp & 15);
            int c = cp >> 1, p = cp & 1;
            int zz = zbase + 2 * zp + p;
            if (FUSE) {
                __align__(16) unsigned short tmp[8] = {0, 0, 0, 0, 0, 0, 0, 0};
                if ((unsigned)xx < DIMV && (unsigned)yy < DIMV && (unsigned)zz < DIMV) {
                    int vox = ((xx * DIMV) + yy) * DIMV + zz;
                    const float* src = Gf + (size_t)vox * CH + c * 8;
                    float sc = inv[vox];
#pragma unroll
                    for (int j = 0; j < 8; ++j) tmp[j] = f2bf(src[j] * sc);
                }
                *(int4*)(slab + (size_t)idx * 8) = *(const int4*)tmp;
            } else {
                int4 val = make_int4(0, 0, 0, 0);
                if ((unsigned)xx < DIMV && (unsigned)yy < DIMV && (unsigned)zz < DIMV)
                    val = *(const int4*)(Gb + (size_t)(((xx * DIMV) + yy) * DIMV + zz) * CH + c * 8);
                *(int4*)(slab + (size_t)idx * 8) = val;
            }
        }
    }
    __syncthreads();

    f32x16 acc[2][2];
#pragma unroll
    for (int ct = 0; ct < 2; ++ct)
#pragma unroll
        for (int nt = 0; nt < 2; ++nt)
#pragma unroll
            for (int r = 0; r < 16; ++r) acc[ct][nt][r] = 0.f;

    const int doff = w * 3;          // per-wave d rotation (0,3,...,21)

    bf16x8 bfr0[8], bfr1[8];
    auto issueB = [&](bf16x8 (&B)[8], int d) {
        const unsigned short* wn = wbuf + (size_t)d * 4096 + lane * 8;
#pragma unroll
        for (int q = 0; q < 8; ++q) B[q] = *(const bf16x8*)(wn + q * 512);
    };
    auto stepCompute = [&](bf16x8 (&B)[8], int d) {
        const int dx = d / 9, dy = (d / 3) % 3, dz = d % 3;
        const int zval = lz + dz;                  // 0..33
        const int zp = zval >> 1, p = zval & 1;
        const int rbase = ((cx + dx) * 6 + (cy0 + dy)) * 17 + zp;
#pragma unroll
        for (int kkl = 0; kkl < 4; ++kkl) {
            const int slot = ((kkl * 2 + kg) * 2 + p) ^ (zp & 15);
            bf16x8 a0 = *(const bf16x8*)(slab + rbase * 128 + slot * 8);
            bf16x8 a1 = *(const bf16x8*)(slab + (rbase + 17) * 128 + slot * 8);
            acc[0][0] = __builtin_amdgcn_mfma_f32_32x32x16_bf16(a0, B[kkl * 2 + 0], acc[0][0], 0, 0, 0);
            acc[1][0] = __builtin_amdgcn_mfma_f32_32x32x16_bf16(a1, B[kkl * 2 + 0], acc[1][0], 0, 0, 0);
            acc[0][1] = __builtin_amdgcn_mfma_f32_32x32x16_bf16(a0, B[kkl * 2 + 1], acc[0][1], 0, 0, 0);
            acc[1][1] = __builtin_amdgcn_mfma_f32_32x32x16_bf16(a1, B[kkl * 2 + 1], acc[1][1], 0, 0, 0);
        }
    };

    {
        int d0 = __builtin_amdgcn_readfirstlane(doff);
        issueB(bfr0, d0);
    }
#pragma unroll
    for (int s = 0; s < 27; ++s) {
        if (s < 26) {
            int dn = doff + s + 1;
            if (dn >= 27) dn -= 27;
            dn = __builtin_amdgcn_readfirstlane(dn);
            if (s & 1) issueB(bfr0, dn); else issueB(bfr1, dn);
        }
        int dc = doff + s;
        if (dc >= 27) dc -= 27;
        dc = __builtin_amdgcn_readfirstlane(dc);
        if (s & 1) stepCompute(bfr1, dc); else stepCompute(bfr0, dc);
    }

    const int x_out = 4 * BX + cx;
#pragma unroll
    for (int ct = 0; ct < 2; ++ct) {
        int y_out = 4 * BY + cy0 + ct;
#pragma unroll
        for (int nt = 0; nt < 2; ++nt) {
            int co = nt * 32 + lz;
            float scale = g[co] * rsqrtf(v[co] + EPSB);
            float shift = be[co] - m[co] * scale;
            float bias = cb[co];
            size_t base = (size_t)((x_out * DIMV) + y_out) * DIMV * CH + co;
#pragma unroll
            for (int r = 0; r < 16; ++r) {
                int zrow = (r & 3) + 8 * (r >> 2) + 4 * kg;
                int z = BZ * 32 + zrow;
                float val = fmaxf(acc[ct][nt][r] + bias, 0.f) * scale + shift;
                out[base + (size_t)z * CH] = f2bf(val);
            }
        }
    }
}

// ---------------- fused point-MLP (MFMA) + trilinear gather + final write ----------------
__global__ __launch_bounds__(256) void mlp_gather(
    const float* __restrict__ x, const unsigned short* __restrict__ wfrag,
    const float* __restrict__ b, const float* __restrict__ g,
    const float* __restrict__ be, const float* __restrict__ m,
    const float* __restrict__ v, const unsigned short* __restrict__ grid,
    const float* __restrict__ pts, float* __restrict__ out, int npts) {
    __shared__ float lds[128 * 64];          // 32 KB
    const int w = threadIdx.x >> 6;
    const int lane = threadIdx.x & 63;
    const int col = lane & 31;
    const int kg = lane >> 5;
    const int p0 = (blockIdx.x * 4 + w) * 32;

    if (p0 < npts) {
        bf16x8 a[4];
        const float* xr = x + (size_t)(p0 + col) * CH + kg * 8;
#pragma unroll
        for (int kk = 0; kk < 4; ++kk) {
            const float* p = xr + kk * 16;
            bf16x8 t;
#pragma unroll
            for (int j = 0; j < 8; ++j) t[j] = (short)f2bf(p[j]);
            a[kk] = t;
        }
        f32x16 acc[2];
#pragma unroll
        for (int nt = 0; nt < 2; ++nt)
#pragma unroll
            for (int r = 0; r < 16; ++r) acc[nt][r] = 0.f;
#pragma unroll
        for (int kk = 0; kk < 4; ++kk) {
            bf16x8 b0 = *(const bf16x8*)(wfrag + (kk * 2 + 0) * 512 + lane * 8);
            bf16x8 b1 = *(const bf16x8*)(wfrag + (kk * 2 + 1) * 512 + lane * 8);
            acc[0] = __builtin_amdgcn_mfma_f32_32x32x16_bf16(a[kk], b0, acc[0], 0, 0, 0);
            acc[1] = __builtin_amdgcn_mfma_f32_32x32x16_bf16(a[kk], b1, acc[1], 0, 0, 0);
        }
#pragma unroll
        for (int nt = 0; nt < 2; ++nt) {
            int co = nt * 32 + col;
            float scale = g[co] * rsqrtf(v[co] + EPSB);
            float shift = be[co] - m[co] * scale;
            float bias = b[co];
#pragma unroll
            for (int r = 0; r < 16; ++r) {
                int row = (r & 3) + 8 * (r >> 2) + 4 * kg;
                float val = fmaxf(acc[nt][r] + bias, 0.f) * scale + shift;
                lds[(w * 32 + row) * 64 + co] = val;
            }
        }
    }
    __syncthreads();

    const int pblk = blockIdx.x * 128;
#pragma unroll 4
    for (int i = 0; i < 32; ++i) {
        int idx = i * 256 + threadIdx.x;
        int pl = idx >> 6;
        int c = idx & 63;
        int pt = pblk + pl;
        if (pt >= npts) break;
        float px = fminf(fmaxf(pts[pt * 3 + 0], 0.f), (float)(DIMV - 1));
        float py = fminf(fmaxf(pts[pt * 3 + 1], 0.f), (float)(DIMV - 1));
        float pz = fminf(fmaxf(pts[pt * 3 + 2], 0.f), (float)(DIMV - 1));
        float fx = floorf(px), fy = floorf(py), fz = floorf(pz);
        float tx = px - fx, ty = py - fy, tz = pz - fz;
        int x0 = (int)fx, y0 = (int)fy, z0 = (int)fz;
        int x1 = min(x0 + 1, DIMV - 1), y1 = min(y0 + 1, DIMV - 1), z1 = min(z0 + 1, DIMV - 1);
        float wx0 = 1.f - tx, wy0 = 1.f - ty, wz0 = 1.f - tz;
        float acc = lds[pl * 64 + c];
        acc = fmaf(wx0 * wy0 * wz0, bf2f(grid[(size_t)(((x0 * DIMV) + y0) * DIMV + z0) * CH + c]), acc);
        acc = fmaf(wx0 * wy0 * tz,  bf2f(grid[(size_t)(((x0 * DIMV) + y0) * DIMV + z1) * CH + c]), acc);
        acc = fmaf(wx0 * ty * wz0,  bf2f(grid[(size_t)(((x0 * DIMV) + y1) * DIMV + z0) * CH + c]), acc);
        acc = fmaf(wx0 * ty * tz,   bf2f(grid[(size_t)(((x0 * DIMV) + y1) * DIMV + z1) * CH + c]), acc);
        acc = fmaf(tx * wy0 * wz0,  bf2f(grid[(size_t)(((x1 * DIMV) + y0) * DIMV + z0) * CH + c]), acc);
        acc = fmaf(tx * wy0 * tz,   bf2f(grid[(size_t)(((x1 * DIMV) + y0) * DIMV + z1) * CH + c]), acc);
        acc = fmaf(tx * ty * wz0,   bf2f(grid[(size_t)(((x1 * DIMV) + y1) * DIMV + z0) * CH + c]), acc);
        acc = fmaf(tx * ty * tz,    bf2f(grid[(size_t)(((x1 * DIMV) + y1) * DIMV + z1) * CH + c]), acc);
        out[(size_t)pt * CH + c] = acc;
    }
}

extern "C" void kernel_launch(void* const* d_in, const int* in_sizes, int n_in,
                              void* d_out, int out_size, void* d_ws, size_t ws_size,
                              hipStream_t stream) {
    const float* inputs = (const float*)d_in[0];
    const float* pt_coords = (const float*)d_in[1];
    const int* voxel_indexes = (const int*)d_in[2];
    const float* ppvi = (const float*)d_in[3];
    const float* w_mlp = (const float*)d_in[4];
    const float* b_mlp = (const float*)d_in[5];
    const float* g0 = (const float*)d_in[6];
    const float* be0 = (const float*)d_in[7];
    const float* m0 = (const float*)d_in[8];
    const float* v0 = (const float*)d_in[9];
    const float* k1 = (const float*)d_in[10];
    const float* cb1 = (const float*)d_in[11];
    const float* g1 = (const float*)d_in[12];
    const float* be1 = (const float*)d_in[13];
    const float* m1 = (const float*)d_in[14];
    const float* v1 = (const float*)d_in[15];
    const float* k2 = (const float*)d_in[16];
    const float* cb2 = (const float*)d_in[17];
    const float* g2 = (const float*)d_in[18];
    const float* be2 = (const float*)d_in[19];
    const float* m2 = (const float*)d_in[20];
    const float* v2 = (const float*)d_in[21];
    float* out = (float*)d_out;

    char* ws = (char*)d_ws;
    // [0, 67.1M):     A fp32 scatter grid; after conv1 done, G3 bf16 reuses [0,33.5M)
    // [67.1M,100.7M): G2 bf16 (conv1 output, conv2 input)
    // [100.7M, +):    wbuf1, wbuf2 (221184 B each), wmlp (8192 B)
    float* A = (float*)ws;
    unsigned short* G3 = (unsigned short*)ws;
    unsigned short* G2 = (unsigned short*)(ws + 67108864);
    unsigned short* wbuf1 = (unsigned short*)(ws + 100663296);
    unsigned short* wbuf2 = (unsigned short*)(ws + 100884480);
    unsigned short* wmlp = (unsigned short*)(ws + 101105664);

    const int n_total = in_sizes[0];           // N * C
    const int npts = n_total / CH;
    const int nblk = (n_total + 255) / 256;
    const size_t grid_elems = (size_t)DIMV * DIMV * DIMV * CH;

    hipMemsetAsync(A, 0, grid_elems * sizeof(float), stream);
    wprep_mlp<<<16, 256, 0, stream>>>(w_mlp, wmlp);
    wprep_kernel<<<432, 256, 0, stream>>>(k1, wbuf1);
    wprep_kernel<<<432, 256, 0, stream>>>(k2, wbuf2);
    scatter_kernel<<<nblk, 256, 0, stream>>>(inputs, voxel_indexes, A, n_total);

    dim3 cgrid(16, 16, 2);
    conv_mfma<1><<<cgrid, 512, 0, stream>>>(nullptr, A, ppvi, wbuf1, cb1, g1, be1, m1, v1, G2);
    conv_mfma<0><<<cgrid, 512, 0, stream>>>(G2, nullptr, nullptr, wbuf2, cb2, g2, be2, m2, v2, G3);

    mlp_gather<<<(npts + 127) / 128, 256, 0, stream>>>(
        inputs, wmlp, b_mlp, g0, be0, m0, v0, G3, pt_coords, out, npts);
}

// Round 10
// 279.314 us; speedup vs baseline: 1.0808x; 1.0259x over previous
//
#include <hip/hip_runtime.h>
#include <hip/hip_bf16.h>

#define DIMV 64
#define CH 64
#define EPSB 1e-3f

using bf16x8 = __attribute__((ext_vector_type(8))) short;
using f32x16 = __attribute__((ext_vector_type(16))) float;

__device__ __forceinline__ unsigned short f2bf(float f) {
    union { float f; unsigned u; } x; x.f = f;
    unsigned r = x.u + 0x7fff + ((x.u >> 16) & 1);   // round-to-nearest-even
    return (unsigned short)(r >> 16);
}
__device__ __forceinline__ float bf2f(unsigned short u) {
    union { unsigned u; float f; } x; x.u = ((unsigned)u) << 16;
    return x.f;
}

__global__ void scatter_kernel(const float* __restrict__ x, const int* __restrict__ idx,
                               float* __restrict__ grid, int n_total) {
    int tid = blockIdx.x * blockDim.x + threadIdx.x;
    if (tid >= n_total) return;
    int n = tid >> 6, c = tid & 63;
    int ix = idx[n * 3 + 0], iy = idx[n * 3 + 1], iz = idx[n * 3 + 2];
    atomicAdd(&grid[(size_t)(((ix * DIMV) + iy) * DIMV + iz) * CH + c], x[tid]);
}

// ---------------- weight repack into MFMA B-fragment layout ----------------
__global__ void wprep_kernel(const float* __restrict__ K, unsigned short* __restrict__ wbuf) {
    int t = blockIdx.x * 256 + threadIdx.x;
    if (t >= 27 * 4 * 2 * 64 * 8) return;
    int j = t & 7;
    int l = (t >> 3) & 63;
    int nt = (t >> 9) & 1;
    int kkl = (t >> 10) & 3;
    int d = t >> 12;
    int ci = kkl * 16 + (l >> 5) * 8 + j;
    int co = nt * 32 + (l & 31);
    wbuf[t] = f2bf(K[((size_t)d * 64 + ci) * 64 + co]);
}

__global__ void wprep_mlp(const float* __restrict__ W, unsigned short* __restrict__ wm) {
    int t = blockIdx.x * 256 + threadIdx.x;
    if (t >= 4 * 2 * 64 * 8) return;
    int j = t & 7;
    int l = (t >> 3) & 63;
    int nt = (t >> 9) & 1;
    int kkl = (t >> 10) & 3;
    int ci = kkl * 16 + (l >> 5) * 8 + j;
    int co = nt * 32 + (l & 31);
    wm[t] = f2bf(W[(size_t)ci * 64 + co]);
}

// ---------------- MFMA conv (r6 structure): 8 waves, wave = 2 y-adjacent cols ----------------
// C-tile 4x4 xy x 32 z per block. Per d: 8 A ds_reads + 8 B global loads -> 16 MFMAs.
// A-slab: 36 cols x 17 z-pairs x 256B = 153 KB. Depth-1 B reg ping-pong, no barriers
// after stage. setprio(1) wraps each d-step MFMA cluster (waves are independent here).
// FUSE=1: stage reads fp32 scatter grid * inv (pack fused). FUSE=0: bf16 grid.
template <int FUSE>
__global__ __launch_bounds__(512) void conv_mfma(
    const unsigned short* __restrict__ Gb, const float* __restrict__ Gf,
    const float* __restrict__ inv, const unsigned short* __restrict__ wbuf,
    const float* __restrict__ cb, const float* __restrict__ g,
    const float* __restrict__ be, const float* __restrict__ m,
    const float* __restrict__ v, unsigned short* __restrict__ out) {
    __shared__ __align__(16) unsigned short slab[612 * 128];   // 156672 B
    const int tid = threadIdx.x;
    const int lane = tid & 63;
    const int w = tid >> 6;          // wave 0..7
    const int cx = w >> 1;           // x-col 0..3
    const int cy0 = 2 * (w & 1);     // y-col base 0 or 2
    const int lz = lane & 31;
    const int kg = lane >> 5;
    const int BX = blockIdx.x, BY = blockIdx.y, BZ = blockIdx.z;
    const int x0 = 4 * BX - 1, y0 = 4 * BY - 1;
    const int zbase = 32 * BZ - 1;   // odd

    // Stage A slab: 9792 chunks of 16B. Pre-swizzled global source, linear LDS
    // write. Slot s at row (col,zp) holds ch-pair chunk cp = s ^ (zp&15).
    for (int it = 0; it < 20; ++it) {
        int idx = it * 512 + tid;
        if (idx < 9792) {
            int s = idx & 15;
            int r = idx >> 4;               // 0..611
            int zp = r % 17;
            int ryx = r / 17;               // 0..35
            int xx = x0 + ryx / 6;
            int yy = y0 + ryx % 6;
            int cp = s ^ (zp & 15);
            int c = cp >> 1, p = cp & 1;
            int zz = zbase + 2 * zp + p;
            if (FUSE) {
                __align__(16) unsigned short tmp[8] = {0, 0, 0, 0, 0, 0, 0, 0};
                if ((unsigned)xx < DIMV && (unsigned)yy < DIMV && (unsigned)zz < DIMV) {
                    int vox = ((xx * DIMV) + yy) * DIMV + zz;
                    const float* src = Gf + (size_t)vox * CH + c * 8;
                    float sc = inv[vox];
#pragma unroll
                    for (int j = 0; j < 8; ++j) tmp[j] = f2bf(src[j] * sc);
                }
                *(int4*)(slab + (size_t)idx * 8) = *(const int4*)tmp;
            } else {
                int4 val = make_int4(0, 0, 0, 0);
                if ((unsigned)xx < DIMV && (unsigned)yy < DIMV && (unsigned)zz < DIMV)
                    val = *(const int4*)(Gb + (size_t)(((xx * DIMV) + yy) * DIMV + zz) * CH + c * 8);
                *(int4*)(slab + (size_t)idx * 8) = val;
            }
        }
    }
    __syncthreads();

    f32x16 acc[2][2];
#pragma unroll
    for (int ct = 0; ct < 2; ++ct)
#pragma unroll
        for (int nt = 0; nt < 2; ++nt)
#pragma unroll
            for (int r = 0; r < 16; ++r) acc[ct][nt][r] = 0.f;

    // B ping-pong prefetch: frag q = kkl*2+nt at wbuf + d*4096 + q*512 + lane*8
    bf16x8 bfr0[8], bfr1[8];
#pragma unroll
    for (int q = 0; q < 8; ++q)
        bfr0[q] = *(const bf16x8*)(wbuf + q * 512 + lane * 8);

#pragma unroll
    for (int d = 0; d < 27; ++d) {
        if (d < 26) {
            const unsigned short* wn = wbuf + (size_t)(d + 1) * 4096;
            if (d & 1) {
#pragma unroll
                for (int q = 0; q < 8; ++q) bfr0[q] = *(const bf16x8*)(wn + q * 512 + lane * 8);
            } else {
#pragma unroll
                for (int q = 0; q < 8; ++q) bfr1[q] = *(const bf16x8*)(wn + q * 512 + lane * 8);
            }
        }
        const int dx = d / 9, dy = (d / 3) % 3, dz = d % 3;
        const int zval = lz + dz;                  // 0..33
        const int zp = zval >> 1, p = zval & 1;
        const int rbase = ((cx + dx) * 6 + (cy0 + dy)) * 17 + zp;
        __builtin_amdgcn_s_setprio(1);
#pragma unroll
        for (int kkl = 0; kkl < 4; ++kkl) {
            const int c = kkl * 2 + kg;
            const int slot = (c * 2 + p) ^ (zp & 15);
            bf16x8 a0 = *(const bf16x8*)(slab + rbase * 128 + slot * 8);
            bf16x8 a1 = *(const bf16x8*)(slab + (rbase + 17) * 128 + slot * 8);
            bf16x8 b0 = (d & 1) ? bfr1[kkl * 2 + 0] : bfr0[kkl * 2 + 0];
            bf16x8 b1 = (d & 1) ? bfr1[kkl * 2 + 1] : bfr0[kkl * 2 + 1];
            acc[0][0] = __builtin_amdgcn_mfma_f32_32x32x16_bf16(a0, b0, acc[0][0], 0, 0, 0);
            acc[1][0] = __builtin_amdgcn_mfma_f32_32x32x16_bf16(a1, b0, acc[1][0], 0, 0, 0);
            acc[0][1] = __builtin_amdgcn_mfma_f32_32x32x16_bf16(a0, b1, acc[0][1], 0, 0, 0);
            acc[1][1] = __builtin_amdgcn_mfma_f32_32x32x16_bf16(a1, b1, acc[1][1], 0, 0, 0);
        }
        __builtin_amdgcn_s_setprio(0);
    }

    const int x_out = 4 * BX + cx;
#pragma unroll
    for (int ct = 0; ct < 2; ++ct) {
        int y_out = 4 * BY + cy0 + ct;
#pragma unroll
        for (int nt = 0; nt < 2; ++nt) {
            int co = nt * 32 + lz;
            float scale = g[co] * rsqrtf(v[co] + EPSB);
            float shift = be[co] - m[co] * scale;
            float bias = cb[co];
            size_t base = (size_t)((x_out * DIMV) + y_out) * DIMV * CH + co;
#pragma unroll
            for (int r = 0; r < 16; ++r) {
                int zrow = (r & 3) + 8 * (r >> 2) + 4 * kg;
                int z = BZ * 32 + zrow;
                float val = fmaxf(acc[ct][nt][r] + bias, 0.f) * scale + shift;
                out[base + (size_t)z * CH] = f2bf(val);
            }
        }
    }
}

// ---------------- fused point-MLP (MFMA) + trilinear gather + final write ----------------
__global__ __launch_bounds__(256) void mlp_gather(
    const float* __restrict__ x, const unsigned short* __restrict__ wfrag,
    const float* __restrict__ b, const float* __restrict__ g,
    const float* __restrict__ be, const float* __restrict__ m,
    const float* __restrict__ v, const unsigned short* __restrict__ grid,
    const float* __restrict__ pts, float* __restrict__ out, int npts) {
    __shared__ float lds[128 * 64];          // 32 KB
    const int w = threadIdx.x >> 6;
    const int lane = threadIdx.x & 63;
    const int col = lane & 31;
    const int kg = lane >> 5;
    const int p0 = (blockIdx.x * 4 + w) * 32;

    if (p0 < npts) {
        bf16x8 a[4];
        const float* xr = x + (size_t)(p0 + col) * CH + kg * 8;
#pragma unroll
        for (int kk = 0; kk < 4; ++kk) {
            const float* p = xr + kk * 16;
            bf16x8 t;
#pragma unroll
            for (int j = 0; j < 8; ++j) t[j] = (short)f2bf(p[j]);
            a[kk] = t;
        }
        f32x16 acc[2];
#pragma unroll
        for (int nt = 0; nt < 2; ++nt)
#pragma unroll
            for (int r = 0; r < 16; ++r) acc[nt][r] = 0.f;
#pragma unroll
        for (int kk = 0; kk < 4; ++kk) {
            bf16x8 b0 = *(const bf16x8*)(wfrag + (kk * 2 + 0) * 512 + lane * 8);
            bf16x8 b1 = *(const bf16x8*)(wfrag + (kk * 2 + 1) * 512 + lane * 8);
            acc[0] = __builtin_amdgcn_mfma_f32_32x32x16_bf16(a[kk], b0, acc[0], 0, 0, 0);
            acc[1] = __builtin_amdgcn_mfma_f32_32x32x16_bf16(a[kk], b1, acc[1], 0, 0, 0);
        }
#pragma unroll
        for (int nt = 0; nt < 2; ++nt) {
            int co = nt * 32 + col;
            float scale = g[co] * rsqrtf(v[co] + EPSB);
            float shift = be[co] - m[co] * scale;
            float bias = b[co];
#pragma unroll
            for (int r = 0; r < 16; ++r) {
                int row = (r & 3) + 8 * (r >> 2) + 4 * kg;
                float val = fmaxf(acc[nt][r] + bias, 0.f) * scale + shift;
                lds[(w * 32 + row) * 64 + co] = val;
            }
        }
    }
    __syncthreads();

    const int pblk = blockIdx.x * 128;
#pragma unroll 4
    for (int i = 0; i < 32; ++i) {
        int idx = i * 256 + threadIdx.x;
        int pl = idx >> 6;
        int c = idx & 63;
        int pt = pblk + pl;
        if (pt >= npts) break;
        float px = fminf(fmaxf(pts[pt * 3 + 0], 0.f), (float)(DIMV - 1));
        float py = fminf(fmaxf(pts[pt * 3 + 1], 0.f), (float)(DIMV - 1));
        float pz = fminf(fmaxf(pts[pt * 3 + 2], 0.f), (float)(DIMV - 1));
        float fx = floorf(px), fy = floorf(py), fz = floorf(pz);
        float tx = px - fx, ty = py - fy, tz = pz - fz;
        int x0 = (int)fx, y0 = (int)fy, z0 = (int)fz;
        int x1 = min(x0 + 1, DIMV - 1), y1 = min(y0 + 1, DIMV - 1), z1 = min(z0 + 1, DIMV - 1);
        float wx0 = 1.f - tx, wy0 = 1.f - ty, wz0 = 1.f - tz;
        float acc = lds[pl * 64 + c];
        acc = fmaf(wx0 * wy0 * wz0, bf2f(grid[(size_t)(((x0 * DIMV) + y0) * DIMV + z0) * CH + c]), acc);
        acc = fmaf(wx0 * wy0 * tz,  bf2f(grid[(size_t)(((x0 * DIMV) + y0) * DIMV + z1) * CH + c]), acc);
        acc = fmaf(wx0 * ty * wz0,  bf2f(grid[(size_t)(((x0 * DIMV) + y1) * DIMV + z0) * CH + c]), acc);
        acc = fmaf(wx0 * ty * tz,   bf2f(grid[(size_t)(((x0 * DIMV) + y1) * DIMV + z1) * CH + c]), acc);
        acc = fmaf(tx * wy0 * wz0,  bf2f(grid[(size_t)(((x1 * DIMV) + y0) * DIMV + z0) * CH + c]), acc);
        acc = fmaf(tx * wy0 * tz,   bf2f(grid[(size_t)(((x1 * DIMV) + y0) * DIMV + z1) * CH + c]), acc);
        acc = fmaf(tx * ty * wz0,   bf2f(grid[(size_t)(((x1 * DIMV) + y1) * DIMV + z0) * CH + c]), acc);
        acc = fmaf(tx * ty * tz,    bf2f(grid[(size_t)(((x1 * DIMV) + y1) * DIMV + z1) * CH + c]), acc);
        out[(size_t)pt * CH + c] = acc;
    }
}

extern "C" void kernel_launch(void* const* d_in, const int* in_sizes, int n_in,
                              void* d_out, int out_size, void* d_ws, size_t ws_size,
                              hipStream_t stream) {
    const float* inputs = (const float*)d_in[0];
    const float* pt_coords = (const float*)d_in[1];
    const int* voxel_indexes = (const int*)d_in[2];
    const float* ppvi = (const float*)d_in[3];
    const float* w_mlp = (const float*)d_in[4];
    const float* b_mlp = (const float*)d_in[5];
    const float* g0 = (const float*)d_in[6];
    const float* be0 = (const float*)d_in[7];
    const float* m0 = (const float*)d_in[8];
    const float* v0 = (const float*)d_in[9];
    const float* k1 = (const float*)d_in[10];
    const float* cb1 = (const float*)d_in[11];
    const float* g1 = (const float*)d_in[12];
    const float* be1 = (const float*)d_in[13];
    const float* m1 = (const float*)d_in[14];
    const float* v1 = (const float*)d_in[15];
    const float* k2 = (const float*)d_in[16];
    const float* cb2 = (const float*)d_in[17];
    const float* g2 = (const float*)d_in[18];
    const float* be2 = (const float*)d_in[19];
    const float* m2 = (const float*)d_in[20];
    const float* v2 = (const float*)d_in[21];
    float* out = (float*)d_out;

    char* ws = (char*)d_ws;
    // [0, 67.1M):     A fp32 scatter grid; after conv1 done, G3 bf16 reuses [0,33.5M)
    // [67.1M,100.7M): G2 bf16 (conv1 output, conv2 input)
    // [100.7M, +):    wbuf1, wbuf2 (221184 B each), wmlp (8192 B)
    float* A = (float*)ws;
    unsigned short* G3 = (unsigned short*)ws;
    unsigned short* G2 = (unsigned short*)(ws + 67108864);
    unsigned short* wbuf1 = (unsigned short*)(ws + 100663296);
    unsigned short* wbuf2 = (unsigned short*)(ws + 100884480);
    unsigned short* wmlp = (unsigned short*)(ws + 101105664);

    const int n_total = in_sizes[0];           // N * C
    const int npts = n_total / CH;
    const int nblk = (n_total + 255) / 256;
    const size_t grid_elems = (size_t)DIMV * DIMV * DIMV * CH;

    hipMemsetAsync(A, 0, grid_elems * sizeof(float), stream);
    wprep_mlp<<<16, 256, 0, stream>>>(w_mlp, wmlp);
    wprep_kernel<<<432, 256, 0, stream>>>(k1, wbuf1);
    wprep_kernel<<<432, 256, 0, stream>>>(k2, wbuf2);
    scatter_kernel<<<nblk, 256, 0, stream>>>(inputs, voxel_indexes, A, n_total);

    dim3 cgrid(16, 16, 2);
    conv_mfma<1><<<cgrid, 512, 0, stream>>>(nullptr, A, ppvi, wbuf1, cb1, g1, be1, m1, v1, G2);
    conv_mfma<0><<<cgrid, 512, 0, stream>>>(G2, nullptr, nullptr, wbuf2, cb2, g2, be2, m2, v2, G3);

    mlp_gather<<<(npts + 127) / 128, 256, 0, stream>>>(
        inputs, wmlp, b_mlp, g0, be0, m0, v0, G3, pt_coords, out, npts);
}